// Round 8
// baseline (888.849 us; speedup 1.0000x reference)
//
#include <hip/hip_runtime.h>
#include <hip/hip_bf16.h>
#include <math.h>

using bf16 = __hip_bfloat16;
using short8  = __attribute__((ext_vector_type(8))) short;
using float4v = __attribute__((ext_vector_type(4))) float;

#define B_   64
#define S_   12
#define N04  307
#define N07  883
#define N08  170
#define BN   (B_ * N04)        // 19648
#define HID  256
#define ENC  256
#define PRE  12
#define UOFF (N04 * HID)       // 78592 flat split point

// extractor geometry (K padded to x64 for MFMA)
constexpr int c_Mi[3]   = {N04, N07, N08};
constexpr int c_Kp[3]   = {320, 896, 192};
constexpr int c_Moff[3] = {0, N04, N04 + N07};
constexpr int c_Aoff[3] = {0, N04 * 320, N04 * 320 + N07 * 896};
constexpr int c_Cb[3]   = {0, 320, 320 + 896};
#define MTOT  (N04 + N07 + N08)   // 1360
#define H0T_LD 1408

// ---------------- static tensor tables ----------------
#define NT 38
constexpr int g_sz[NT] = {
    39296, 113024, 21760, 235776, 94249, 779689, 28900,
    32768, 256, 65536, 256, 256, 256, 1,
    32768, 256, 65536, 256, 256, 256, 1,
    32768, 256, 65536, 256, 256, 256, 1,
    131584, 512, 65792, 256, 65536, 1, 131072, 256, 3072, 12
};
struct Tables { int off[NT + 1]; int blk[NT + 1]; };
constexpr Tables mk_tables() {
    Tables t{};
    t.off[0] = 0; t.blk[0] = 0;
    for (int i = 0; i < NT; ++i) {
        t.off[i + 1] = t.off[i] + g_sz[i];
        t.blk[i + 1] = t.blk[i] + (g_sz[i] + 1023) / 1024;
    }
    return t;
}
constexpr Tables g_tbl = mk_tables();

// fast sigmoid/tanh (saturation-safe: exp->inf => rcp->0)
static __device__ __forceinline__ float fsigmoid(float t) {
    return __builtin_amdgcn_rcpf(1.f + __expf(-t));
}
static __device__ __forceinline__ float ftanh(float t) {
    return 1.f - 2.f * __builtin_amdgcn_rcpf(__expf(2.f * t) + 1.f);
}

// m -> (b, nn) split by 307 via magic multiply (valid for m < 9.5e8)
static __device__ __forceinline__ void bsplit(int m, int& b, int& nn) {
    b  = (int)(((unsigned long long)(unsigned)m * 27980243ull) >> 33);
    nn = m - b * N04;
}

// ---------------- dtype sniffer ----------------
__global__ void sniff_kernel(const unsigned short* raw, int* flag)
{
    __shared__ int sh[256];
    int t = threadIdx.x, cnt = 0;
    for (int i = t; i < 2048; i += 256) {
        unsigned int w = ((unsigned int)raw[i]) << 16;
        float a = fabsf(__uint_as_float(w));
        if (a > 1e-3f && a < 100.f) cnt++;
    }
    sh[t] = cnt; __syncthreads();
    for (int off = 128; off > 0; off >>= 1) {
        if (t < off) sh[t] += sh[t + off];
        __syncthreads();
    }
    if (t == 0) *flag = (sh[0] > 1536) ? 1 : 0;
}

struct Ptrs { const void* p[NT]; };

__global__ __launch_bounds__(256) void convert_all(Ptrs a, float* arena, const int* flag)
{
    const int bf = *flag;
    int b = blockIdx.x;
    int t = 0;
    while (b >= g_tbl.blk[t + 1]) ++t;
    const int base = (b - g_tbl.blk[t]) * 1024;
    const int n = g_sz[t];
    const void* src = a.p[t];
    float* dst = arena + g_tbl.off[t];
#pragma unroll
    for (int k = 0; k < 4; ++k) {
        int j = base + k * 256 + threadIdx.x;
        if (j < n)
            dst[j] = bf ? __bfloat162float(((const bf16*)src)[j]) : ((const float*)src)[j];
    }
}

// ---------------- weight prep: GRU fragment-PACKED bf16 B matrices ----------------
// Packed layout (per 16-col x 32-k MFMA tile): tile = (n>>4)*(K>>5) + (k>>5);
// within tile, lane = ((k>>3)&3)*16 + (n&15), elem = k&7. Fragment load in the
// GEMM is then base + tile*1024B + lane*16B -> perfectly coalesced dwordx4 from L2.
__global__ __launch_bounds__(256) void prep_weights(const float* w1, const float* w2, const float* wl,
                                                    bf16* WgP, bf16* WcP, bf16* WlP)
{
    int id = blockIdx.x * 256 + threadIdx.x;
    if (id < 131072) {                    // WgP: N=512, K=256  (32 ntiles x 8 kc)
        int tile = id >> 9, within = id & 511;
        int lane = within >> 3, e = within & 7;
        int n = (tile >> 3) * 16 + (lane & 15);
        int k = (tile & 7) * 32 + (lane >> 4) * 8 + e;
        WgP[id] = __float2bfloat16(w1[(size_t)(1 + k) * 512 + n]);
    } else if (id < 196608) {             // WcP: N=256, K=256  (16 x 8)
        int r = id - 131072;
        int tile = r >> 9, within = r & 511;
        int lane = within >> 3, e = within & 7;
        int n = (tile >> 3) * 16 + (lane & 15);
        int k = (tile & 7) * 32 + (lane >> 4) * 8 + e;
        WcP[r] = __float2bfloat16(w2[(size_t)(1 + k) * 256 + n]);
    } else if (id < 262144) {             // WlP: N=256, K=256
        int r = id - 196608;
        int tile = r >> 9, within = r & 511;
        int lane = within >> 3, e = within & 7;
        int n = (tile >> 3) * 16 + (lane & 15);
        int k = (tile & 7) * 32 + (lane >> 4) * 8 + e;
        WlP[r] = __float2bfloat16(wl[(size_t)k * 256 + n]);
    }
}

// ---------------- extractor operand prep (deg fused in) ----------------
__global__ __launch_bounds__(256) void prep_adjB(const float* a4, const float* a7, const float* a8,
                                                 bf16* adjB, float* deg)
{
    int z = blockIdx.z;
    int Mi = c_Mi[z], Kp = c_Kp[z];
    int m = blockIdx.x;
    if (m >= Mi) return;
    const float* src = (z == 0) ? a4 : (z == 1) ? a7 : a8;
    bf16* dst = adjB + c_Aoff[z] + (size_t)m * Kp;
    float s = 0.f;
    for (int c = threadIdx.x; c < Kp; c += 256) {
        float v = (c < Mi) ? src[(size_t)m * Mi + c] : 0.f;
        dst[c] = __float2bfloat16(v);
        s += v;
    }
    __shared__ float sh[256];
    sh[threadIdx.x] = s; __syncthreads();
    for (int off = 128; off > 0; off >>= 1) {
        if (threadIdx.x < off) sh[threadIdx.x] += sh[threadIdx.x + off];
        __syncthreads();
    }
    if (threadIdx.x == 0) deg[c_Moff[z] + m] = sh[0];
}

__global__ __launch_bounds__(256) void prep_transposes(
    const float* v4, const float* v7, const float* v8,
    const float* w1a, const float* w1b, const float* w1c,
    const float* w2a, const float* w2b, const float* w2c,
    const float* featW, const float* linW, const float* outW,
    bf16* vecB, bf16* W1T, bf16* W2T, bf16* featWT, bf16* linW2T, bf16* outWP)
{
    int id = blockIdx.x * 256 + threadIdx.x;
    if (id < 174080) {                       // vecB [1360][128]
        int r = id >> 7, c = id & 127;
        float v = (r < N04) ? v4[(size_t)r * 128 + c]
                : (r < N04 + N07) ? v7[(size_t)(r - N04) * 128 + c]
                : v8[(size_t)(r - N04 - N07) * 128 + c];
        vecB[id] = __float2bfloat16(v);
    } else if (id < 174080 + 98304) {        // W1T [3][256][128]
        int r = id - 174080; int z = r >> 15; int rem = r & 32767;
        int n = rem >> 7, k = rem & 127;
        const float* w = (z == 0) ? w1a : (z == 1) ? w1b : w1c;
        W1T[r] = __float2bfloat16(w[(size_t)k * 256 + n]);
    } else if (id < 272384 + 196608) {       // W2T [3][256][256]
        int r = id - 272384; int z = r >> 16; int rem = r & 65535;
        int n = rem >> 8, k = rem & 255;
        const float* w = (z == 0) ? w2a : (z == 1) ? w2b : w2c;
        W2T[r] = __float2bfloat16(w[(size_t)k * 256 + n]);
    } else if (id < 468992 + 65536) {        // featWT
        int r = id - 468992; int n = r >> 8, k = r & 255;
        featWT[r] = __float2bfloat16(featW[(size_t)k * 256 + n]);
    } else if (id < 534528 + 65536) {        // linW2T = linW[256:512]^T
        int r = id - 534528; int n = r >> 8, k = r & 255;
        linW2T[r] = __float2bfloat16(linW[(size_t)(256 + k) * 256 + n]);
    } else if (id < 600064 + 16384) {        // outWP packed: N=64 (rows>=12 zero), K=256
        int r = id - 600064;
        int tile = r >> 9, within = r & 511;
        int lane = within >> 3, e = within & 7;
        int p = (tile >> 3) * 16 + (lane & 15);
        int k = (tile & 7) * 32 + (lane >> 4) * 8 + e;
        outWP[r] = __float2bfloat16((p < PRE) ? outW[(size_t)k * PRE + p] : 0.f);
    }
}
#define PREP_T_TOT (600064 + 16384)

// ---------------- 64x64-tile MFMA GEMM, z-merged, runtime K (extractors) ----------------
struct GemmZ {
    const unsigned short* A[3];
    const unsigned short* BT[3];
    int M[3]; int K[3]; int lda[3]; int ldb[3];
};

template <typename EP>
__global__ __launch_bounds__(256) void gemm_mfma64(GemmZ p, int Nv, EP ep)
{
    const int z = blockIdx.z;
    // --- XCD-chunked bijective remap of (x,y) ---
    const int gx = gridDim.x, gy = gridDim.y;
    const int nwg = gx * gy;
    const int flat = blockIdx.y * gx + blockIdx.x;   // hw dispatch order: x fastest
    const int xcd = flat & 7, lin = flat >> 3;
    const int q = nwg >> 3, r = nwg & 7;
    const int wg = (xcd < r ? xcd * (q + 1) : r * (q + 1) + (xcd - r) * q) + lin;
    const int bx = wg / gy;        // A-slab index: consecutive wg share bx
    const int by = wg - bx * gy;   // n-tile

    const int M = p.M[z], K = p.K[z], lda = p.lda[z], ldb = p.ldb[z];
    const int m0 = bx * 64;
    const int n0 = by * 64;
    if (m0 >= M) return;
    __shared__ __align__(16) unsigned short As[64 * 72];
    __shared__ __align__(16) unsigned short Bs[64 * 72];
    const int t = threadIdx.x;
    const int srow  = t >> 2;           // 0..63
    const int skoff = (t & 3) * 16;     // 0,16,32,48 shorts
    const int lane = t & 63;
    const int w  = t >> 6;
    const int wm = (w & 1) * 32;
    const int wn = (w >> 1) * 32;
    const int l15 = lane & 15;
    const int l4  = lane >> 4;

    float4v acc[2][2];
#pragma unroll
    for (int i = 0; i < 2; ++i)
#pragma unroll
        for (int j = 0; j < 2; ++j) acc[i][j] = (float4v)(0.f);

    const int gm = m0 + srow;
    const bool avalid = (gm < M);
    const unsigned short* aptr = p.A[z]  + (size_t)gm * lda + skoff;
    const unsigned short* bptr = p.BT[z] + (size_t)(n0 + srow) * ldb + skoff;
    unsigned short* asw = &As[srow * 72 + skoff];
    unsigned short* bsw = &Bs[srow * 72 + skoff];
    const uint4 z4 = {0, 0, 0, 0};

    for (int kt = 0; kt < K; kt += 64) {
        uint4 av0 = avalid ? *(const uint4*)(aptr + kt)     : z4;
        uint4 av1 = avalid ? *(const uint4*)(aptr + kt + 8) : z4;
        uint4 bv0 = *(const uint4*)(bptr + kt);
        uint4 bv1 = *(const uint4*)(bptr + kt + 8);
        __syncthreads();
        *(uint4*)(asw)     = av0;
        *(uint4*)(asw + 8) = av1;
        *(uint4*)(bsw)     = bv0;
        *(uint4*)(bsw + 8) = bv1;
        __syncthreads();
#pragma unroll
        for (int ks = 0; ks < 2; ++ks) {
            short8 af[2], bq[2];
#pragma unroll
            for (int mi = 0; mi < 2; ++mi)
                af[mi] = *(const short8*)&As[(wm + mi * 16 + l15) * 72 + ks * 32 + l4 * 8];
#pragma unroll
            for (int ni = 0; ni < 2; ++ni)
                bq[ni] = *(const short8*)&Bs[(wn + ni * 16 + l15) * 72 + ks * 32 + l4 * 8];
#pragma unroll
            for (int mi = 0; mi < 2; ++mi)
#pragma unroll
                for (int ni = 0; ni < 2; ++ni)
                    acc[mi][ni] = __builtin_amdgcn_mfma_f32_16x16x32_bf16(af[mi], bq[ni], acc[mi][ni], 0, 0, 0);
        }
    }
#pragma unroll
    for (int mi = 0; mi < 2; ++mi) {
#pragma unroll
        for (int r2 = 0; r2 < 4; ++r2) {
            int m = m0 + wm + mi * 16 + l4 * 4 + r2;
            if (m >= M) continue;
#pragma unroll
            for (int ni = 0; ni < 2; ++ni) {
                int n = n0 + wn + ni * 16 + l15;
                if (n < Nv) ep(z, m, n, acc[mi][ni][r2]);
            }
        }
    }
}

// ---------------- 64-row GEMM, K=256, packed-B direct, full-K A staging (GRU/pred) ----------------
// All of K staged once (64x256 A slab = 33KB LDS, stride 264 keeps the verified
// mod-32 bank profile): each thread owns a 16-short slice per 64-short chunk ->
// EIGHT dwordx4 loads (2 per chunk: +0 and +8 shorts) issued in one burst (one
// latency exposure), one ds_write burst, ONE barrier, then 8 back-to-back kc
// MFMA iterations from LDS. Replaces the 4x{load,barrier,write,barrier,compute}
// chain (8 barriers -> 1). B (weights) L2-resident, packed fragments:
// base + lane*16B coalesced dwordx4. kc order 0..7 unchanged -> bit-identical.
struct GemmB { const unsigned short* A; const unsigned short* Bp; int M; };

template <int NTF, typename EP>
__global__ __launch_bounds__(256, 4) void gemm_bd(GemmB p, int Nv, EP ep)
{
    // XCD-chunked bijective remap (consecutive wg share the A slab)
    const int gx = gridDim.x, gy = gridDim.y;
    const int nwg = gx * gy;
    const int flat = blockIdx.y * gx + blockIdx.x;
    const int xcd = flat & 7, lin = flat >> 3;
    const int q = nwg >> 3, r = nwg & 7;
    const int wg = (xcd < r ? xcd * (q + 1) : r * (q + 1) + (xcd - r) * q) + lin;
    const int bx = wg / gy;
    const int by = wg - bx * gy;
    const int m0 = bx * 64;
    const int n0 = by * (32 * NTF);

    __shared__ __align__(16) unsigned short As[64 * 264];
    const int t = threadIdx.x;
    const int srow  = t >> 2;          // 0..63
    const int skoff = (t & 3) * 16;    // 0,16,32,48 shorts
    const int lane = t & 63;
    const int w  = t >> 6;
    const int wm = (w & 1) * 32;
    const int wn = (w >> 1) * (16 * NTF);
    const int l15 = lane & 15;
    const int l4  = lane >> 4;

    float4v acc[2][NTF];
#pragma unroll
    for (int i = 0; i < 2; ++i)
#pragma unroll
        for (int j = 0; j < NTF; ++j) acc[i][j] = (float4v)(0.f);

    // stage ALL K: this thread's 64 shorts = 8 x dwordx4, one pipelined burst
    const unsigned short* aptr = p.A + (size_t)(m0 + srow) * 256 + skoff;  // M % 64 == 0
    uint4 av[8];
#pragma unroll
    for (int kt = 0; kt < 4; ++kt) {
        av[kt * 2]     = *(const uint4*)(aptr + kt * 64);
        av[kt * 2 + 1] = *(const uint4*)(aptr + kt * 64 + 8);
    }
    unsigned short* asw = &As[srow * 264 + skoff];
#pragma unroll
    for (int kt = 0; kt < 4; ++kt) {
        *(uint4*)(asw + kt * 64)     = av[kt * 2];
        *(uint4*)(asw + kt * 64 + 8) = av[kt * 2 + 1];
    }
    __syncthreads();

    const unsigned short* bbase = p.Bp + (((size_t)((n0 + wn) >> 4) * 8) << 9) + (lane << 3);
#pragma unroll
    for (int kc = 0; kc < 8; ++kc) {
        short8 af[2], bq[NTF];
#pragma unroll
        for (int mi = 0; mi < 2; ++mi)
            af[mi] = *(const short8*)&As[(wm + mi * 16 + l15) * 264 + kc * 32 + l4 * 8];
#pragma unroll
        for (int ni = 0; ni < NTF; ++ni)
            bq[ni] = *(const short8*)(bbase + (((size_t)(ni * 8 + kc)) << 9));
#pragma unroll
        for (int mi = 0; mi < 2; ++mi)
#pragma unroll
            for (int ni = 0; ni < NTF; ++ni)
                acc[mi][ni] = __builtin_amdgcn_mfma_f32_16x16x32_bf16(af[mi], bq[ni], acc[mi][ni], 0, 0, 0);
    }
#pragma unroll
    for (int mi = 0; mi < 2; ++mi) {
#pragma unroll
        for (int r2 = 0; r2 < 4; ++r2) {
            const int m = m0 + wm + mi * 16 + l4 * 4 + r2;
#pragma unroll
            for (int ni = 0; ni < NTF; ++ni) {
                const int n = n0 + wn + ni * 16 + l15;
                if (n < Nv) ep(0, m, n, acc[mi][ni][r2]);
            }
        }
    }
}

// ---------------- extractor epilogues ----------------
struct EPg1 {   // h0 = vec@W1 + b1 ; write fp32 + transposed bf16
    const float* b1[3]; float* h0F; bf16* h0T;
    __device__ void operator()(int z, int m, int n, float v) const {
        v += b1[z][n];
        int gr = c_Moff[z] + m;
        h0F[(size_t)gr * 256 + n] = v;
        h0T[(size_t)n * H0T_LD + c_Cb[z] + m] = __float2bfloat16(v);
    }
};
struct EPg2 {   // h1 = pooled/deg + eps*h0
    const float* deg; const float* h0F; float* h1F; const float* eps[3];
    __device__ void operator()(int z, int m, int n, float v) const {
        int gr = c_Moff[z] + m;
        h1F[(size_t)gr * 256 + n] = v / deg[gr] + eps[z][0] * h0F[(size_t)gr * 256 + n];
    }
};
struct EPg3 {   // f = norm(h1)@W2 + b2 -> d_out (+ f4 bf16 copy for fp2)
    const float* b2[3]; void* outbase; size_t ooff[3]; const int* flag; bf16* f4B;
    __device__ void operator()(int z, int m, int n, float v) const {
        v += b2[z][n];
        size_t i = ooff[z] + (size_t)m * 256 + n;
        if (*flag) ((bf16*)outbase)[i] = __float2bfloat16(v);
        else       ((float*)outbase)[i] = v;
        if (z == 0) f4B[(size_t)m * 256 + n] = __float2bfloat16(v);
    }
};
struct EPfp2a { // fpre = f4@featW + featb (bf16)
    const float* sb; bf16* fpreB;
    __device__ void operator()(int z, int m, int n, float v) const {
        fpreB[(size_t)m * 256 + n] = __float2bfloat16(v + sb[0]);
    }
};
struct EPfp2b { // fp2 = fpre@linW[256:] (fp32)
    float* fp2;
    __device__ void operator()(int z, int m, int n, float v) const {
        fp2[(size_t)m * 256 + n] = v;
    }
};
struct EPpred { // pred = h@outW + outb -> d_out
    const float* ob; void* outbase; const int* flag;
    __device__ void operator()(int z, int m, int n, float v) const {
        v += ob[n];
        size_t i = (size_t)m * PRE + n;
        if (*flag) ((bf16*)outbase)[i] = __float2bfloat16(v);
        else       ((float*)outbase)[i] = v;
    }
};

// ---------------- GRU epilogues (all-bf16 state) ----------------
struct EPgates3 {   // g = sigmoid(.); r-half -> rh = r*h (bf16), u-half -> ub (bf16)
    bf16* rh; bf16* ub; const bf16* hB;
    const float* b1; const float* w1r0; const float* feat; int s;
    __device__ void operator()(int z, int m, int n, float v) const {
        int b, nn; bsplit(m, b, nn);
        float x = feat[((size_t)b * S_ + s) * N04 + nn];
        float g = fsigmoid(v + b1[n] + x * w1r0[n]);
        int p = nn * 512 + n;                 // flat per-batch gate index
        int base = b * UOFF;
        if (p < UOFF) {
            int idx = base + p;
            rh[idx] = __float2bfloat16(g * __bfloat162float(hB[idx]));
        } else {
            ub[base + (p - UOFF)] = __float2bfloat16(g);
        }
    }
};
struct EPcand3 {    // c = tanh(.); uhc = u*h + (1-u)*c (bf16)
    bf16* uhc; const bf16* ub; const bf16* hB;
    const float* b2; const float* w2r0; const float* feat; int s;
    __device__ void operator()(int z, int m, int n, float v) const {
        int b, nn; bsplit(m, b, nn);
        float x = feat[((size_t)b * S_ + s) * N04 + nn];
        float c = ftanh(v + b2[n] + x * w2r0[n]);
        size_t idx = (size_t)m * 256 + n;
        float u = __bfloat162float(ub[idx]);
        float h = __bfloat162float(hB[idx]);
        uhc[idx] = __float2bfloat16(u * h + (1.f - u) * c);
    }
};
struct EPlin3 {     // h_next = v + lin_b + fp2 (bf16)
    bf16* hB; const float* lb; const float* fp2;
    __device__ void operator()(int z, int m, int n, float v) const {
        int b, nn; bsplit(m, b, nn);
        hB[(size_t)m * 256 + n] = __float2bfloat16(v + lb[n] + fp2[(size_t)nn * 256 + n]);
    }
};

// ---------------- step-0 closed form ----------------
__global__ __launch_bounds__(256) void init_step0(const float* feat,
                                                  const float* b1, const float* w1r0,
                                                  const float* b2, const float* w2r0,
                                                  bf16* uhc)
{
    int m = blockIdx.x, n = threadIdx.x;
    int b, nn; bsplit(m, b, nn);
    const float* fb = feat + (size_t)b * S_ * N04;   // s = 0 row
    float c = ftanh(b2[n] + fb[nn] * w2r0[n]);
    int p = UOFF + nn * 256 + n;
    int gn = p >> 9, gc = p & 511;
    float u = fsigmoid(b1[gc] + fb[gn] * w1r0[gc]);
    uhc[(size_t)m * 256 + n] = __float2bfloat16((1.f - u) * c);
}

// ---------------- merged small kernels ----------------
__global__ __launch_bounds__(256) void stats_all(const float* h1F, float* mu, float* rstd)
{
    int z = blockIdx.z;
    int Mi = c_Mi[z], moff = c_Moff[z];
    int j = blockIdx.x;
    int t = threadIdx.x;
    float s = 0.f, ss = 0.f;
    for (int i = t; i < Mi; i += 256) {
        float v = h1F[(size_t)(moff + i) * 256 + j];
        s += v; ss += v * v;
    }
    __shared__ float sh[256], sh2[256];
    sh[t] = s; sh2[t] = ss;
    __syncthreads();
    for (int off = 128; off > 0; off >>= 1) {
        if (t < off) { sh[t] += sh[t + off]; sh2[t] += sh2[t + off]; }
        __syncthreads();
    }
    if (t == 0) {
        float m = sh[0] / (float)Mi;
        float var = sh2[0] / (float)Mi - m * m;
        mu[z * 256 + j] = m;
        rstd[z * 256 + j] = rsqrtf(var + 1e-5f);
    }
}

__global__ __launch_bounds__(256) void norm_all(const float* h1F, const float* mu, const float* rstd,
                                                const float* ga, const float* gb, const float* gc,
                                                const float* ba, const float* bb, const float* bc,
                                                bf16* nh1B)
{
    int r = blockIdx.x;
    int n = threadIdx.x;
    int z = (r < N04) ? 0 : (r < N04 + N07) ? 1 : 2;
    const float* g  = (z == 0) ? ga : (z == 1) ? gb : gc;
    const float* bt = (z == 0) ? ba : (z == 1) ? bb : bc;
    float v = (h1F[(size_t)r * 256 + n] - mu[z * 256 + n]) * rstd[z * 256 + n] * g[n] + bt[n];
    nh1B[(size_t)r * 256 + n] = __float2bfloat16(v);
}

extern "C" void kernel_launch(void* const* d_in, const int* in_sizes, int n_in,
                              void* d_out, int out_size, void* d_ws, size_t ws_size,
                              hipStream_t stream)
{
    char* wp = (char*)d_ws;
    auto carve = [&](size_t bytes) -> void* {
        void* p = (void*)wp;
        wp += (bytes + 255) & ~(size_t)255;
        return p;
    };
    float* arena = (float*)carve((size_t)g_tbl.off[NT] * 4);
    int*   flag  = (int*)carve(256);
    bf16*  hb_a  = (bf16*)carve((size_t)BN * HID * 2);
    bf16*  hb_b  = (bf16*)carve((size_t)BN * HID * 2);
    bf16*  rh    = (bf16*)carve((size_t)BN * HID * 2);
    bf16*  uhc   = (bf16*)carve((size_t)BN * HID * 2);
    bf16*  ubufB = (bf16*)carve((size_t)BN * HID * 2);
    bf16*  WgP   = (bf16*)carve((size_t)512 * 256 * 2);
    bf16*  WcP   = (bf16*)carve((size_t)256 * 256 * 2);
    bf16*  WlP   = (bf16*)carve((size_t)256 * 256 * 2);
    bf16*  vecB  = (bf16*)carve((size_t)MTOT * 128 * 2);
    bf16*  adjB  = (bf16*)carve((size_t)(N04 * 320 + N07 * 896 + N08 * 192) * 2);
    bf16*  W1T   = (bf16*)carve((size_t)3 * 256 * 128 * 2);
    bf16*  W2T   = (bf16*)carve((size_t)3 * 256 * 256 * 2);
    bf16*  featWT= (bf16*)carve((size_t)256 * 256 * 2);
    bf16*  linW2T= (bf16*)carve((size_t)256 * 256 * 2);
    bf16*  outWP = (bf16*)carve((size_t)64 * 256 * 2);
    float* h0F   = (float*)carve((size_t)MTOT * 256 * 4);
    bf16*  h0T   = (bf16*)carve((size_t)256 * H0T_LD * 2);
    float* h1F   = (float*)carve((size_t)MTOT * 256 * 4);
    bf16*  nh1B  = (bf16*)carve((size_t)MTOT * 256 * 2);
    float* degb  = (float*)carve((size_t)MTOT * 4);
    float* mub   = (float*)carve(3 * 256 * 4);
    float* rstdb = (float*)carve(3 * 256 * 4);
    bf16*  f4B   = (bf16*)carve((size_t)N04 * 256 * 2);
    bf16*  fpreB = (bf16*)carve((size_t)N04 * 256 * 2);
    float* fp2   = (float*)carve((size_t)N04 * 256 * 4);

    // --- dtype sniff + canonical fp32 conversion ---
    sniff_kernel<<<1, 256, 0, stream>>>((const unsigned short*)d_in[0], flag);
    Ptrs ptrs;
    for (int i = 0; i < NT; ++i) ptrs.p[i] = d_in[i];
    convert_all<<<g_tbl.blk[NT], 256, 0, stream>>>(ptrs, arena, flag);

    auto A = [&](int i) -> const float* { return arena + g_tbl.off[i]; };

    // --- operand prep ---
    prep_weights<<<1024, 256, 0, stream>>>(A(28), A(30), A(34), WgP, WcP, WlP);
    prep_adjB<<<dim3(N07, 1, 3), 256, 0, stream>>>(A(4), A(5), A(6), adjB, degb);
    prep_transposes<<<(PREP_T_TOT + 255) / 256, 256, 0, stream>>>(
        A(0), A(1), A(2), A(7), A(14), A(21), A(9), A(16), A(23),
        A(32), A(34), A(36), vecB, W1T, W2T, featWT, linW2T, outWP);

    hipMemsetAsync(h0T, 0, (size_t)256 * H0T_LD * 2, stream);

    const size_t o_f4 = (size_t)B_ * N04 * PRE;
    const size_t o_f7 = o_f4 + (size_t)N04 * ENC;
    const size_t o_f8 = o_f7 + (size_t)N07 * ENC;

    // --- E1: h0 = vec@W1 + b1 ---
    {
        GemmZ p;
        for (int z = 0; z < 3; ++z) {
            p.A[z] = (const unsigned short*)(vecB + (size_t)c_Moff[z] * 128);
            p.BT[z] = (const unsigned short*)(W1T + (size_t)z * 256 * 128);
            p.M[z] = c_Mi[z]; p.K[z] = 128; p.lda[z] = 128; p.ldb[z] = 128;
        }
        EPg1 ep{{A(8), A(15), A(22)}, h0F, h0T};
        gemm_mfma64<<<dim3(14, 4, 3), 256, 0, stream>>>(p, 256, ep);
    }
    // --- E2: h1 = (adj@h0)/deg + eps*h0 ---
    {
        GemmZ p;
        for (int z = 0; z < 3; ++z) {
            p.A[z] = (const unsigned short*)(adjB + c_Aoff[z]);
            p.BT[z] = (const unsigned short*)(h0T + c_Cb[z]);
            p.M[z] = c_Mi[z]; p.K[z] = c_Kp[z]; p.lda[z] = c_Kp[z]; p.ldb[z] = H0T_LD;
        }
        EPg2 ep{degb, h0F, h1F, {A(13), A(20), A(27)}};
        gemm_mfma64<<<dim3(14, 4, 3), 256, 0, stream>>>(p, 256, ep);
    }
    // --- BN stats + normalize ---
    stats_all<<<dim3(256, 1, 3), 256, 0, stream>>>(h1F, mub, rstdb);
    norm_all<<<MTOT, 256, 0, stream>>>(h1F, mub, rstdb, A(11), A(18), A(25), A(12), A(19), A(26), nh1B);
    // --- E3: f = nh1@W2 + b2 ---
    {
        GemmZ p;
        for (int z = 0; z < 3; ++z) {
            p.A[z] = (const unsigned short*)(nh1B + (size_t)c_Moff[z] * 256);
            p.BT[z] = (const unsigned short*)(W2T + (size_t)z * 256 * 256);
            p.M[z] = c_Mi[z]; p.K[z] = 256; p.lda[z] = 256; p.ldb[z] = 256;
        }
        EPg3 ep{{A(10), A(17), A(24)}, d_out, {o_f4, o_f7, o_f8}, flag, f4B};
        gemm_mfma64<<<dim3(14, 4, 3), 256, 0, stream>>>(p, 256, ep);
    }
    // --- fp2 = (f4@featW + featb) @ linW[256:512] ---
    {
        GemmZ p{};
        p.A[0] = (const unsigned short*)f4B; p.BT[0] = (const unsigned short*)featWT;
        p.M[0] = N04; p.K[0] = 256; p.lda[0] = 256; p.ldb[0] = 256;
        gemm_mfma64<<<dim3(5, 4, 1), 256, 0, stream>>>(p, 256, EPfp2a{A(33), fpreB});
        p.A[0] = (const unsigned short*)fpreB; p.BT[0] = (const unsigned short*)linW2T;
        gemm_mfma64<<<dim3(5, 4, 1), 256, 0, stream>>>(p, 256, EPfp2b{fp2});
    }

    // --- GRU scan: 64-row MFMA, packed-B direct, full-K staging, all-bf16 state ---
    const float* feat = A(3);
    bf16* hcB = hb_a;
    bf16* hnB = hb_b;
    for (int s = 0; s < S_; ++s) {
        if (s == 0) {
            // h=0: gates+cand GEMM terms are exactly zero -> closed form
            init_step0<<<BN, 256, 0, stream>>>(feat, A(29), A(28), A(31), A(30), uhc);
        } else {
            GemmB pg{(const unsigned short*)hcB, (const unsigned short*)WgP, BN};
            gemm_bd<2><<<dim3(BN / 64, 8, 1), 256, 0, stream>>>(pg, 512,
                EPgates3{rh, ubufB, hcB, A(29), A(28), feat, s});
            GemmB pc{(const unsigned short*)rh, (const unsigned short*)WcP, BN};
            gemm_bd<2><<<dim3(BN / 64, 4, 1), 256, 0, stream>>>(pc, 256,
                EPcand3{uhc, ubufB, hcB, A(31), A(30), feat, s});
        }
        GemmB pl{(const unsigned short*)uhc, (const unsigned short*)WlP, BN};
        gemm_bd<2><<<dim3(BN / 64, 4, 1), 256, 0, stream>>>(pl, 256,
            EPlin3{hnB, A(35), fp2});
        bf16* tb = hcB; hcB = hnB; hnB = tb;
    }

    // --- pred = h@outW + outb (packed-B, N padded to 64, guard n<12) ---
    {
        GemmB pp{(const unsigned short*)hcB, (const unsigned short*)outWP, BN};
        gemm_bd<2><<<dim3(BN / 64, 1, 1), 256, 0, stream>>>(pp, PRE, EPpred{A(37), d_out, flag});
    }
}

// Round 9
// 739.781 us; speedup vs baseline: 1.2015x; 1.2015x over previous
//
#include <hip/hip_runtime.h>
#include <hip/hip_bf16.h>
#include <math.h>

using bf16 = __hip_bfloat16;
using short8  = __attribute__((ext_vector_type(8))) short;
using float4v = __attribute__((ext_vector_type(4))) float;

#define B_   64
#define S_   12
#define N04  307
#define N07  883
#define N08  170
#define BN   (B_ * N04)        // 19648
#define HID  256
#define ENC  256
#define PRE  12
#define UOFF (N04 * HID)       // 78592 flat split point

// extractor geometry (K padded to x64 for MFMA)
constexpr int c_Mi[3]   = {N04, N07, N08};
constexpr int c_Kp[3]   = {320, 896, 192};
constexpr int c_Moff[3] = {0, N04, N04 + N07};
constexpr int c_Aoff[3] = {0, N04 * 320, N04 * 320 + N07 * 896};
constexpr int c_Cb[3]   = {0, 320, 320 + 896};
#define MTOT  (N04 + N07 + N08)   // 1360
#define H0T_LD 1408

// ---------------- static tensor tables ----------------
#define NT 38
constexpr int g_sz[NT] = {
    39296, 113024, 21760, 235776, 94249, 779689, 28900,
    32768, 256, 65536, 256, 256, 256, 1,
    32768, 256, 65536, 256, 256, 256, 1,
    32768, 256, 65536, 256, 256, 256, 1,
    131584, 512, 65792, 256, 65536, 1, 131072, 256, 3072, 12
};
struct Tables { int off[NT + 1]; int blk[NT + 1]; };
constexpr Tables mk_tables() {
    Tables t{};
    t.off[0] = 0; t.blk[0] = 0;
    for (int i = 0; i < NT; ++i) {
        t.off[i + 1] = t.off[i] + g_sz[i];
        t.blk[i + 1] = t.blk[i] + (g_sz[i] + 1023) / 1024;
    }
    return t;
}
constexpr Tables g_tbl = mk_tables();

// fast sigmoid/tanh (saturation-safe: exp->inf => rcp->0)
static __device__ __forceinline__ float fsigmoid(float t) {
    return __builtin_amdgcn_rcpf(1.f + __expf(-t));
}
static __device__ __forceinline__ float ftanh(float t) {
    return 1.f - 2.f * __builtin_amdgcn_rcpf(__expf(2.f * t) + 1.f);
}

// m -> (b, nn) split by 307 via magic multiply (valid for m < 9.5e8)
static __device__ __forceinline__ void bsplit(int m, int& b, int& nn) {
    b  = (int)(((unsigned long long)(unsigned)m * 27980243ull) >> 33);
    nn = m - b * N04;
}

// ---------------- dtype sniffer ----------------
__global__ void sniff_kernel(const unsigned short* raw, int* flag)
{
    __shared__ int sh[256];
    int t = threadIdx.x, cnt = 0;
    for (int i = t; i < 2048; i += 256) {
        unsigned int w = ((unsigned int)raw[i]) << 16;
        float a = fabsf(__uint_as_float(w));
        if (a > 1e-3f && a < 100.f) cnt++;
    }
    sh[t] = cnt; __syncthreads();
    for (int off = 128; off > 0; off >>= 1) {
        if (t < off) sh[t] += sh[t + off];
        __syncthreads();
    }
    if (t == 0) *flag = (sh[0] > 1536) ? 1 : 0;
}

struct Ptrs { const void* p[NT]; };

__global__ __launch_bounds__(256) void convert_all(Ptrs a, float* arena, const int* flag)
{
    const int bf = *flag;
    int b = blockIdx.x;
    int t = 0;
    while (b >= g_tbl.blk[t + 1]) ++t;
    const int base = (b - g_tbl.blk[t]) * 1024;
    const int n = g_sz[t];
    const void* src = a.p[t];
    float* dst = arena + g_tbl.off[t];
#pragma unroll
    for (int k = 0; k < 4; ++k) {
        int j = base + k * 256 + threadIdx.x;
        if (j < n)
            dst[j] = bf ? __bfloat162float(((const bf16*)src)[j]) : ((const float*)src)[j];
    }
}

// ---------------- weight prep: GRU fragment-PACKED bf16 B matrices ----------------
// Packed layout (per 16-col x 32-k MFMA tile): tile = (n>>4)*(K>>5) + (k>>5);
// within tile, lane = ((k>>3)&3)*16 + (n&15), elem = k&7. Fragment load in the
// GEMM is then base + tile*1024B + lane*16B -> perfectly coalesced dwordx4 from L2.
__global__ __launch_bounds__(256) void prep_weights(const float* w1, const float* w2, const float* wl,
                                                    bf16* WgP, bf16* WcP, bf16* WlP)
{
    int id = blockIdx.x * 256 + threadIdx.x;
    if (id < 131072) {                    // WgP: N=512, K=256  (32 ntiles x 8 kc)
        int tile = id >> 9, within = id & 511;
        int lane = within >> 3, e = within & 7;
        int n = (tile >> 3) * 16 + (lane & 15);
        int k = (tile & 7) * 32 + (lane >> 4) * 8 + e;
        WgP[id] = __float2bfloat16(w1[(size_t)(1 + k) * 512 + n]);
    } else if (id < 196608) {             // WcP: N=256, K=256  (16 x 8)
        int r = id - 131072;
        int tile = r >> 9, within = r & 511;
        int lane = within >> 3, e = within & 7;
        int n = (tile >> 3) * 16 + (lane & 15);
        int k = (tile & 7) * 32 + (lane >> 4) * 8 + e;
        WcP[r] = __float2bfloat16(w2[(size_t)(1 + k) * 256 + n]);
    } else if (id < 262144) {             // WlP: N=256, K=256
        int r = id - 196608;
        int tile = r >> 9, within = r & 511;
        int lane = within >> 3, e = within & 7;
        int n = (tile >> 3) * 16 + (lane & 15);
        int k = (tile & 7) * 32 + (lane >> 4) * 8 + e;
        WlP[r] = __float2bfloat16(wl[(size_t)k * 256 + n]);
    }
}

// ---------------- extractor operand prep (deg fused in) ----------------
__global__ __launch_bounds__(256) void prep_adjB(const float* a4, const float* a7, const float* a8,
                                                 bf16* adjB, float* deg)
{
    int z = blockIdx.z;
    int Mi = c_Mi[z], Kp = c_Kp[z];
    int m = blockIdx.x;
    if (m >= Mi) return;
    const float* src = (z == 0) ? a4 : (z == 1) ? a7 : a8;
    bf16* dst = adjB + c_Aoff[z] + (size_t)m * Kp;
    float s = 0.f;
    for (int c = threadIdx.x; c < Kp; c += 256) {
        float v = (c < Mi) ? src[(size_t)m * Mi + c] : 0.f;
        dst[c] = __float2bfloat16(v);
        s += v;
    }
    __shared__ float sh[256];
    sh[threadIdx.x] = s; __syncthreads();
    for (int off = 128; off > 0; off >>= 1) {
        if (threadIdx.x < off) sh[threadIdx.x] += sh[threadIdx.x + off];
        __syncthreads();
    }
    if (threadIdx.x == 0) deg[c_Moff[z] + m] = sh[0];
}

__global__ __launch_bounds__(256) void prep_transposes(
    const float* v4, const float* v7, const float* v8,
    const float* w1a, const float* w1b, const float* w1c,
    const float* w2a, const float* w2b, const float* w2c,
    const float* featW, const float* linW, const float* outW,
    bf16* vecB, bf16* W1T, bf16* W2T, bf16* featWT, bf16* linW2T, bf16* outWP)
{
    int id = blockIdx.x * 256 + threadIdx.x;
    if (id < 174080) {                       // vecB [1360][128]
        int r = id >> 7, c = id & 127;
        float v = (r < N04) ? v4[(size_t)r * 128 + c]
                : (r < N04 + N07) ? v7[(size_t)(r - N04) * 128 + c]
                : v8[(size_t)(r - N04 - N07) * 128 + c];
        vecB[id] = __float2bfloat16(v);
    } else if (id < 174080 + 98304) {        // W1T [3][256][128]
        int r = id - 174080; int z = r >> 15; int rem = r & 32767;
        int n = rem >> 7, k = rem & 127;
        const float* w = (z == 0) ? w1a : (z == 1) ? w1b : w1c;
        W1T[r] = __float2bfloat16(w[(size_t)k * 256 + n]);
    } else if (id < 272384 + 196608) {       // W2T [3][256][256]
        int r = id - 272384; int z = r >> 16; int rem = r & 65535;
        int n = rem >> 8, k = rem & 255;
        const float* w = (z == 0) ? w2a : (z == 1) ? w2b : w2c;
        W2T[r] = __float2bfloat16(w[(size_t)k * 256 + n]);
    } else if (id < 468992 + 65536) {        // featWT
        int r = id - 468992; int n = r >> 8, k = r & 255;
        featWT[r] = __float2bfloat16(featW[(size_t)k * 256 + n]);
    } else if (id < 534528 + 65536) {        // linW2T = linW[256:512]^T
        int r = id - 534528; int n = r >> 8, k = r & 255;
        linW2T[r] = __float2bfloat16(linW[(size_t)(256 + k) * 256 + n]);
    } else if (id < 600064 + 16384) {        // outWP packed: N=64 (rows>=12 zero), K=256
        int r = id - 600064;
        int tile = r >> 9, within = r & 511;
        int lane = within >> 3, e = within & 7;
        int p = (tile >> 3) * 16 + (lane & 15);
        int k = (tile & 7) * 32 + (lane >> 4) * 8 + e;
        outWP[r] = __float2bfloat16((p < PRE) ? outW[(size_t)k * PRE + p] : 0.f);
    }
}
#define PREP_T_TOT (600064 + 16384)

// ---------------- 64x64-tile MFMA GEMM, z-merged, runtime K (extractors) ----------------
struct GemmZ {
    const unsigned short* A[3];
    const unsigned short* BT[3];
    int M[3]; int K[3]; int lda[3]; int ldb[3];
};

template <typename EP>
__global__ __launch_bounds__(256) void gemm_mfma64(GemmZ p, int Nv, EP ep)
{
    const int z = blockIdx.z;
    // --- XCD-chunked bijective remap of (x,y) ---
    const int gx = gridDim.x, gy = gridDim.y;
    const int nwg = gx * gy;
    const int flat = blockIdx.y * gx + blockIdx.x;   // hw dispatch order: x fastest
    const int xcd = flat & 7, lin = flat >> 3;
    const int q = nwg >> 3, r = nwg & 7;
    const int wg = (xcd < r ? xcd * (q + 1) : r * (q + 1) + (xcd - r) * q) + lin;
    const int bx = wg / gy;        // A-slab index: consecutive wg share bx
    const int by = wg - bx * gy;   // n-tile

    const int M = p.M[z], K = p.K[z], lda = p.lda[z], ldb = p.ldb[z];
    const int m0 = bx * 64;
    const int n0 = by * 64;
    if (m0 >= M) return;
    __shared__ __align__(16) unsigned short As[64 * 72];
    __shared__ __align__(16) unsigned short Bs[64 * 72];
    const int t = threadIdx.x;
    const int srow  = t >> 2;           // 0..63
    const int skoff = (t & 3) * 16;     // 0,16,32,48 shorts
    const int lane = t & 63;
    const int w  = t >> 6;
    const int wm = (w & 1) * 32;
    const int wn = (w >> 1) * 32;
    const int l15 = lane & 15;
    const int l4  = lane >> 4;

    float4v acc[2][2];
#pragma unroll
    for (int i = 0; i < 2; ++i)
#pragma unroll
        for (int j = 0; j < 2; ++j) acc[i][j] = (float4v)(0.f);

    const int gm = m0 + srow;
    const bool avalid = (gm < M);
    const unsigned short* aptr = p.A[z]  + (size_t)gm * lda + skoff;
    const unsigned short* bptr = p.BT[z] + (size_t)(n0 + srow) * ldb + skoff;
    unsigned short* asw = &As[srow * 72 + skoff];
    unsigned short* bsw = &Bs[srow * 72 + skoff];
    const uint4 z4 = {0, 0, 0, 0};

    for (int kt = 0; kt < K; kt += 64) {
        uint4 av0 = avalid ? *(const uint4*)(aptr + kt)     : z4;
        uint4 av1 = avalid ? *(const uint4*)(aptr + kt + 8) : z4;
        uint4 bv0 = *(const uint4*)(bptr + kt);
        uint4 bv1 = *(const uint4*)(bptr + kt + 8);
        __syncthreads();
        *(uint4*)(asw)     = av0;
        *(uint4*)(asw + 8) = av1;
        *(uint4*)(bsw)     = bv0;
        *(uint4*)(bsw + 8) = bv1;
        __syncthreads();
#pragma unroll
        for (int ks = 0; ks < 2; ++ks) {
            short8 af[2], bq[2];
#pragma unroll
            for (int mi = 0; mi < 2; ++mi)
                af[mi] = *(const short8*)&As[(wm + mi * 16 + l15) * 72 + ks * 32 + l4 * 8];
#pragma unroll
            for (int ni = 0; ni < 2; ++ni)
                bq[ni] = *(const short8*)&Bs[(wn + ni * 16 + l15) * 72 + ks * 32 + l4 * 8];
#pragma unroll
            for (int mi = 0; mi < 2; ++mi)
#pragma unroll
                for (int ni = 0; ni < 2; ++ni)
                    acc[mi][ni] = __builtin_amdgcn_mfma_f32_16x16x32_bf16(af[mi], bq[ni], acc[mi][ni], 0, 0, 0);
        }
    }
#pragma unroll
    for (int mi = 0; mi < 2; ++mi) {
#pragma unroll
        for (int r2 = 0; r2 < 4; ++r2) {
            int m = m0 + wm + mi * 16 + l4 * 4 + r2;
            if (m >= M) continue;
#pragma unroll
            for (int ni = 0; ni < 2; ++ni) {
                int n = n0 + wn + ni * 16 + l15;
                if (n < Nv) ep(z, m, n, acc[mi][ni][r2]);
            }
        }
    }
}

// ---------------- 64-row GEMM, K=256, packed-B direct from global (GRU/pred) ----------------
// R4-verified structure (744 us): chunked 4x{load,barrier,write,barrier,compute},
// small LDS (9.2KB), high occupancy. B (weights) is L2-resident -> no LDS staging
// (common-mistake #7); packed fragment layout makes the B load base + lane*16B
// (coalesced 1KB dwordx4). NTF=2 instantiation is instruction-identical to R4.
struct GemmB { const unsigned short* A; const unsigned short* Bp; int M; };

template <int NTF, typename EP>
__global__ __launch_bounds__(256, 4) void gemm_bd(GemmB p, int Nv, EP ep)
{
    // XCD-chunked bijective remap (consecutive wg share the A slab)
    const int gx = gridDim.x, gy = gridDim.y;
    const int nwg = gx * gy;
    const int flat = blockIdx.y * gx + blockIdx.x;
    const int xcd = flat & 7, lin = flat >> 3;
    const int q = nwg >> 3, r = nwg & 7;
    const int wg = (xcd < r ? xcd * (q + 1) : r * (q + 1) + (xcd - r) * q) + lin;
    const int bx = wg / gy;
    const int by = wg - bx * gy;
    const int m0 = bx * 64;
    const int n0 = by * (32 * NTF);

    __shared__ __align__(16) unsigned short As[64 * 72];
    const int t = threadIdx.x;
    const int srow  = t >> 2;
    const int skoff = (t & 3) * 16;
    const int lane = t & 63;
    const int w  = t >> 6;
    const int wm = (w & 1) * 32;
    const int wn = (w >> 1) * (16 * NTF);
    const int l15 = lane & 15;
    const int l4  = lane >> 4;

    float4v acc[2][NTF];
#pragma unroll
    for (int i = 0; i < 2; ++i)
#pragma unroll
        for (int j = 0; j < NTF; ++j) acc[i][j] = (float4v)(0.f);

    const unsigned short* aptr = p.A + (size_t)(m0 + srow) * 256 + skoff;  // M % 64 == 0
    unsigned short* asw = &As[srow * 72 + skoff];
    const unsigned short* bbase = p.Bp + (((size_t)((n0 + wn) >> 4) * 8) << 9) + (lane << 3);

#pragma unroll
    for (int kt = 0; kt < 4; ++kt) {
        uint4 av0 = *(const uint4*)(aptr + kt * 64);
        uint4 av1 = *(const uint4*)(aptr + kt * 64 + 8);
        __syncthreads();
        *(uint4*)(asw)     = av0;
        *(uint4*)(asw + 8) = av1;
        __syncthreads();
#pragma unroll
        for (int ks = 0; ks < 2; ++ks) {
            const int kc = kt * 2 + ks;
            short8 af[2], bq[NTF];
#pragma unroll
            for (int mi = 0; mi < 2; ++mi)
                af[mi] = *(const short8*)&As[(wm + mi * 16 + l15) * 72 + ks * 32 + l4 * 8];
#pragma unroll
            for (int ni = 0; ni < NTF; ++ni)
                bq[ni] = *(const short8*)(bbase + (((size_t)(ni * 8 + kc)) << 9));
#pragma unroll
            for (int mi = 0; mi < 2; ++mi)
#pragma unroll
                for (int ni = 0; ni < NTF; ++ni)
                    acc[mi][ni] = __builtin_amdgcn_mfma_f32_16x16x32_bf16(af[mi], bq[ni], acc[mi][ni], 0, 0, 0);
        }
    }
#pragma unroll
    for (int mi = 0; mi < 2; ++mi) {
#pragma unroll
        for (int r2 = 0; r2 < 4; ++r2) {
            const int m = m0 + wm + mi * 16 + l4 * 4 + r2;
#pragma unroll
            for (int ni = 0; ni < NTF; ++ni) {
                const int n = n0 + wn + ni * 16 + l15;
                if (n < Nv) ep(0, m, n, acc[mi][ni][r2]);
            }
        }
    }
}

// ---------------- extractor epilogues ----------------
struct EPg1 {   // h0 = vec@W1 + b1 ; write fp32 + transposed bf16
    const float* b1[3]; float* h0F; bf16* h0T;
    __device__ void operator()(int z, int m, int n, float v) const {
        v += b1[z][n];
        int gr = c_Moff[z] + m;
        h0F[(size_t)gr * 256 + n] = v;
        h0T[(size_t)n * H0T_LD + c_Cb[z] + m] = __float2bfloat16(v);
    }
};
struct EPg2 {   // h1 = pooled/deg + eps*h0
    const float* deg; const float* h0F; float* h1F; const float* eps[3];
    __device__ void operator()(int z, int m, int n, float v) const {
        int gr = c_Moff[z] + m;
        h1F[(size_t)gr * 256 + n] = v / deg[gr] + eps[z][0] * h0F[(size_t)gr * 256 + n];
    }
};
struct EPg3 {   // f = norm(h1)@W2 + b2 -> d_out (+ f4 bf16 copy for fp2)
    const float* b2[3]; void* outbase; size_t ooff[3]; const int* flag; bf16* f4B;
    __device__ void operator()(int z, int m, int n, float v) const {
        v += b2[z][n];
        size_t i = ooff[z] + (size_t)m * 256 + n;
        if (*flag) ((bf16*)outbase)[i] = __float2bfloat16(v);
        else       ((float*)outbase)[i] = v;
        if (z == 0) f4B[(size_t)m * 256 + n] = __float2bfloat16(v);
    }
};
struct EPfp2a { // fpre = f4@featW + featb (bf16)
    const float* sb; bf16* fpreB;
    __device__ void operator()(int z, int m, int n, float v) const {
        fpreB[(size_t)m * 256 + n] = __float2bfloat16(v + sb[0]);
    }
};
struct EPfp2b { // fp2 = fpre@linW[256:] (fp32)
    float* fp2;
    __device__ void operator()(int z, int m, int n, float v) const {
        fp2[(size_t)m * 256 + n] = v;
    }
};
struct EPpred { // pred = h@outW + outb -> d_out
    const float* ob; void* outbase; const int* flag;
    __device__ void operator()(int z, int m, int n, float v) const {
        v += ob[n];
        size_t i = (size_t)m * PRE + n;
        if (*flag) ((bf16*)outbase)[i] = __float2bfloat16(v);
        else       ((float*)outbase)[i] = v;
    }
};

// ---------------- GRU epilogues (all-bf16 state) ----------------
struct EPgates3 {   // g = sigmoid(.); r-half -> rh = r*h (bf16), u-half -> ub (bf16)
    bf16* rh; bf16* ub; const bf16* hB;
    const float* b1; const float* w1r0; const float* feat; int s;
    __device__ void operator()(int z, int m, int n, float v) const {
        int b, nn; bsplit(m, b, nn);
        float x = feat[((size_t)b * S_ + s) * N04 + nn];
        float g = fsigmoid(v + b1[n] + x * w1r0[n]);
        int p = nn * 512 + n;                 // flat per-batch gate index
        int base = b * UOFF;
        if (p < UOFF) {
            int idx = base + p;
            rh[idx] = __float2bfloat16(g * __bfloat162float(hB[idx]));
        } else {
            ub[base + (p - UOFF)] = __float2bfloat16(g);
        }
    }
};
struct EPcand3 {    // c = tanh(.); uhc = u*h + (1-u)*c (bf16)
    bf16* uhc; const bf16* ub; const bf16* hB;
    const float* b2; const float* w2r0; const float* feat; int s;
    __device__ void operator()(int z, int m, int n, float v) const {
        int b, nn; bsplit(m, b, nn);
        float x = feat[((size_t)b * S_ + s) * N04 + nn];
        float c = ftanh(v + b2[n] + x * w2r0[n]);
        size_t idx = (size_t)m * 256 + n;
        float u = __bfloat162float(ub[idx]);
        float h = __bfloat162float(hB[idx]);
        uhc[idx] = __float2bfloat16(u * h + (1.f - u) * c);
    }
};
struct EPlin3 {     // h_next = v + lin_b + fp2 (bf16)
    bf16* hB; const float* lb; const float* fp2;
    __device__ void operator()(int z, int m, int n, float v) const {
        int b, nn; bsplit(m, b, nn);
        hB[(size_t)m * 256 + n] = __float2bfloat16(v + lb[n] + fp2[(size_t)nn * 256 + n]);
    }
};

// ---------------- step-0 closed form ----------------
__global__ __launch_bounds__(256) void init_step0(const float* feat,
                                                  const float* b1, const float* w1r0,
                                                  const float* b2, const float* w2r0,
                                                  bf16* uhc)
{
    int m = blockIdx.x, n = threadIdx.x;
    int b, nn; bsplit(m, b, nn);
    const float* fb = feat + (size_t)b * S_ * N04;   // s = 0 row
    float c = ftanh(b2[n] + fb[nn] * w2r0[n]);
    int p = UOFF + nn * 256 + n;
    int gn = p >> 9, gc = p & 511;
    float u = fsigmoid(b1[gc] + fb[gn] * w1r0[gc]);
    uhc[(size_t)m * 256 + n] = __float2bfloat16((1.f - u) * c);
}

// ---------------- merged small kernels ----------------
__global__ __launch_bounds__(256) void stats_all(const float* h1F, float* mu, float* rstd)
{
    int z = blockIdx.z;
    int Mi = c_Mi[z], moff = c_Moff[z];
    int j = blockIdx.x;
    int t = threadIdx.x;
    float s = 0.f, ss = 0.f;
    for (int i = t; i < Mi; i += 256) {
        float v = h1F[(size_t)(moff + i) * 256 + j];
        s += v; ss += v * v;
    }
    __shared__ float sh[256], sh2[256];
    sh[t] = s; sh2[t] = ss;
    __syncthreads();
    for (int off = 128; off > 0; off >>= 1) {
        if (t < off) { sh[t] += sh[t + off]; sh2[t] += sh2[t + off]; }
        __syncthreads();
    }
    if (t == 0) {
        float m = sh[0] / (float)Mi;
        float var = sh2[0] / (float)Mi - m * m;
        mu[z * 256 + j] = m;
        rstd[z * 256 + j] = rsqrtf(var + 1e-5f);
    }
}

__global__ __launch_bounds__(256) void norm_all(const float* h1F, const float* mu, const float* rstd,
                                                const float* ga, const float* gb, const float* gc,
                                                const float* ba, const float* bb, const float* bc,
                                                bf16* nh1B)
{
    int r = blockIdx.x;
    int n = threadIdx.x;
    int z = (r < N04) ? 0 : (r < N04 + N07) ? 1 : 2;
    const float* g  = (z == 0) ? ga : (z == 1) ? gb : gc;
    const float* bt = (z == 0) ? ba : (z == 1) ? bb : bc;
    float v = (h1F[(size_t)r * 256 + n] - mu[z * 256 + n]) * rstd[z * 256 + n] * g[n] + bt[n];
    nh1B[(size_t)r * 256 + n] = __float2bfloat16(v);
}

extern "C" void kernel_launch(void* const* d_in, const int* in_sizes, int n_in,
                              void* d_out, int out_size, void* d_ws, size_t ws_size,
                              hipStream_t stream)
{
    char* wp = (char*)d_ws;
    auto carve = [&](size_t bytes) -> void* {
        void* p = (void*)wp;
        wp += (bytes + 255) & ~(size_t)255;
        return p;
    };
    float* arena = (float*)carve((size_t)g_tbl.off[NT] * 4);
    int*   flag  = (int*)carve(256);
    bf16*  hb_a  = (bf16*)carve((size_t)BN * HID * 2);
    bf16*  hb_b  = (bf16*)carve((size_t)BN * HID * 2);
    bf16*  rh    = (bf16*)carve((size_t)BN * HID * 2);
    bf16*  uhc   = (bf16*)carve((size_t)BN * HID * 2);
    bf16*  ubufB = (bf16*)carve((size_t)BN * HID * 2);
    bf16*  WgP   = (bf16*)carve((size_t)512 * 256 * 2);
    bf16*  WcP   = (bf16*)carve((size_t)256 * 256 * 2);
    bf16*  WlP   = (bf16*)carve((size_t)256 * 256 * 2);
    bf16*  vecB  = (bf16*)carve((size_t)MTOT * 128 * 2);
    bf16*  adjB  = (bf16*)carve((size_t)(N04 * 320 + N07 * 896 + N08 * 192) * 2);
    bf16*  W1T   = (bf16*)carve((size_t)3 * 256 * 128 * 2);
    bf16*  W2T   = (bf16*)carve((size_t)3 * 256 * 256 * 2);
    bf16*  featWT= (bf16*)carve((size_t)256 * 256 * 2);
    bf16*  linW2T= (bf16*)carve((size_t)256 * 256 * 2);
    bf16*  outWP = (bf16*)carve((size_t)64 * 256 * 2);
    float* h0F   = (float*)carve((size_t)MTOT * 256 * 4);
    bf16*  h0T   = (bf16*)carve((size_t)256 * H0T_LD * 2);
    float* h1F   = (float*)carve((size_t)MTOT * 256 * 4);
    bf16*  nh1B  = (bf16*)carve((size_t)MTOT * 256 * 2);
    float* degb  = (float*)carve((size_t)MTOT * 4);
    float* mub   = (float*)carve(3 * 256 * 4);
    float* rstdb = (float*)carve(3 * 256 * 4);
    bf16*  f4B   = (bf16*)carve((size_t)N04 * 256 * 2);
    bf16*  fpreB = (bf16*)carve((size_t)N04 * 256 * 2);
    float* fp2   = (float*)carve((size_t)N04 * 256 * 4);

    // --- dtype sniff + canonical fp32 conversion ---
    sniff_kernel<<<1, 256, 0, stream>>>((const unsigned short*)d_in[0], flag);
    Ptrs ptrs;
    for (int i = 0; i < NT; ++i) ptrs.p[i] = d_in[i];
    convert_all<<<g_tbl.blk[NT], 256, 0, stream>>>(ptrs, arena, flag);

    auto A = [&](int i) -> const float* { return arena + g_tbl.off[i]; };

    // --- operand prep ---
    prep_weights<<<1024, 256, 0, stream>>>(A(28), A(30), A(34), WgP, WcP, WlP);
    prep_adjB<<<dim3(N07, 1, 3), 256, 0, stream>>>(A(4), A(5), A(6), adjB, degb);
    prep_transposes<<<(PREP_T_TOT + 255) / 256, 256, 0, stream>>>(
        A(0), A(1), A(2), A(7), A(14), A(21), A(9), A(16), A(23),
        A(32), A(34), A(36), vecB, W1T, W2T, featWT, linW2T, outWP);

    hipMemsetAsync(h0T, 0, (size_t)256 * H0T_LD * 2, stream);

    const size_t o_f4 = (size_t)B_ * N04 * PRE;
    const size_t o_f7 = o_f4 + (size_t)N04 * ENC;
    const size_t o_f8 = o_f7 + (size_t)N07 * ENC;

    // --- E1: h0 = vec@W1 + b1 ---
    {
        GemmZ p;
        for (int z = 0; z < 3; ++z) {
            p.A[z] = (const unsigned short*)(vecB + (size_t)c_Moff[z] * 128);
            p.BT[z] = (const unsigned short*)(W1T + (size_t)z * 256 * 128);
            p.M[z] = c_Mi[z]; p.K[z] = 128; p.lda[z] = 128; p.ldb[z] = 128;
        }
        EPg1 ep{{A(8), A(15), A(22)}, h0F, h0T};
        gemm_mfma64<<<dim3(14, 4, 3), 256, 0, stream>>>(p, 256, ep);
    }
    // --- E2: h1 = (adj@h0)/deg + eps*h0 ---
    {
        GemmZ p;
        for (int z = 0; z < 3; ++z) {
            p.A[z] = (const unsigned short*)(adjB + c_Aoff[z]);
            p.BT[z] = (const unsigned short*)(h0T + c_Cb[z]);
            p.M[z] = c_Mi[z]; p.K[z] = c_Kp[z]; p.lda[z] = c_Kp[z]; p.ldb[z] = H0T_LD;
        }
        EPg2 ep{degb, h0F, h1F, {A(13), A(20), A(27)}};
        gemm_mfma64<<<dim3(14, 4, 3), 256, 0, stream>>>(p, 256, ep);
    }
    // --- BN stats + normalize ---
    stats_all<<<dim3(256, 1, 3), 256, 0, stream>>>(h1F, mub, rstdb);
    norm_all<<<MTOT, 256, 0, stream>>>(h1F, mub, rstdb, A(11), A(18), A(25), A(12), A(19), A(26), nh1B);
    // --- E3: f = nh1@W2 + b2 ---
    {
        GemmZ p;
        for (int z = 0; z < 3; ++z) {
            p.A[z] = (const unsigned short*)(nh1B + (size_t)c_Moff[z] * 256);
            p.BT[z] = (const unsigned short*)(W2T + (size_t)z * 256 * 256);
            p.M[z] = c_Mi[z]; p.K[z] = 256; p.lda[z] = 256; p.ldb[z] = 256;
        }
        EPg3 ep{{A(10), A(17), A(24)}, d_out, {o_f4, o_f7, o_f8}, flag, f4B};
        gemm_mfma64<<<dim3(14, 4, 3), 256, 0, stream>>>(p, 256, ep);
    }
    // --- fp2 = (f4@featW + featb) @ linW[256:512] ---
    {
        GemmZ p{};
        p.A[0] = (const unsigned short*)f4B; p.BT[0] = (const unsigned short*)featWT;
        p.M[0] = N04; p.K[0] = 256; p.lda[0] = 256; p.ldb[0] = 256;
        gemm_mfma64<<<dim3(5, 4, 1), 256, 0, stream>>>(p, 256, EPfp2a{A(33), fpreB});
        p.A[0] = (const unsigned short*)fpreB; p.BT[0] = (const unsigned short*)linW2T;
        gemm_mfma64<<<dim3(5, 4, 1), 256, 0, stream>>>(p, 256, EPfp2b{fp2});
    }

    // --- GRU scan: 64-row MFMA, packed-B direct, chunked staging (R4), bf16 state ---
    const float* feat = A(3);
    bf16* hcB = hb_a;
    bf16* hnB = hb_b;
    for (int s = 0; s < S_; ++s) {
        if (s == 0) {
            // h=0: gates+cand GEMM terms are exactly zero -> closed form
            init_step0<<<BN, 256, 0, stream>>>(feat, A(29), A(28), A(31), A(30), uhc);
        } else {
            GemmB pg{(const unsigned short*)hcB, (const unsigned short*)WgP, BN};
            gemm_bd<2><<<dim3(BN / 64, 8, 1), 256, 0, stream>>>(pg, 512,
                EPgates3{rh, ubufB, hcB, A(29), A(28), feat, s});
            GemmB pc{(const unsigned short*)rh, (const unsigned short*)WcP, BN};
            gemm_bd<2><<<dim3(BN / 64, 4, 1), 256, 0, stream>>>(pc, 256,
                EPcand3{uhc, ubufB, hcB, A(31), A(30), feat, s});
        }
        GemmB pl{(const unsigned short*)uhc, (const unsigned short*)WlP, BN};
        gemm_bd<2><<<dim3(BN / 64, 4, 1), 256, 0, stream>>>(pl, 256,
            EPlin3{hnB, A(35), fp2});
        bf16* tb = hcB; hcB = hnB; hnB = tb;
    }

    // --- pred = h@outW + outb (packed-B, N padded to 64, guard n<12) ---
    {
        GemmB pp{(const unsigned short*)hcB, (const unsigned short*)outWP, BN};
        gemm_bd<2><<<dim3(BN / 64, 1, 1), 256, 0, stream>>>(pp, PRE, EPpred{A(37), d_out, flag});
    }
}